// Round 17
// baseline (343.937 us; speedup 1.0000x reference)
//
#include <hip/hip_runtime.h>
#include <stdint.h>

#define DI __device__ __forceinline__

typedef __attribute__((ext_vector_type(8))) _Float16 f16x8;
typedef __attribute__((ext_vector_type(4))) float f32x4;
typedef __attribute__((ext_vector_type(4))) int   i32x4;
typedef __attribute__((ext_vector_type(4))) float fvec4;
typedef __attribute__((ext_vector_type(8))) unsigned short u16x8;
typedef __attribute__((ext_vector_type(4))) unsigned short u16x4;

constexpr int S2   = 2048;
constexpr int NHD  = 4096;   // NH*HD (q width)
constexpr int KVD  = 1024;   // NKV*HD
constexpr int QKVW = 6144;   // q+k+v fused width
constexpr float SCALE_LOG2E = 0.08838834764831845f * 1.4426950408889634f; // 1/sqrt(128)*log2(e)

DI unsigned short f32_f16(float f) {
    union { _Float16 h; unsigned short u; } v;
    v.h = (_Float16)f;
    return v.u;
}

DI f32x4 mfma16(f16x8 a, f16x8 b, f32x4 c) {
    return __builtin_amdgcn_mfma_f32_16x16x32_f16(a, b, c, 0, 0, 0);
}

DI void load_lds16(const void* g, void* l) {
    __builtin_amdgcn_global_load_lds(
        (const __attribute__((address_space(1))) void*)(uintptr_t)g,
        (__attribute__((address_space(3))) void*)(uintptr_t)l, 16, 0, 0);
}

// ---------------- W4 dequant body: (q - z) * s -> f16 -----------------------
DI void prep_body(const int* __restrict__ qw, const float* __restrict__ sc,
                  const int* __restrict__ zp, unsigned short* __restrict__ outW,
                  int blk, int tid) {
    long long t = (long long)blk * 256 + tid;
    long long base = t * 8;
    int n = (int)(base >> 12);
    int g = (int)((base >> 7) & 31);
    float s = sc[n * 32 + g];
    int   z = zp[n * 32 + g];
    i32x4 a = *(const i32x4*)(qw + base);
    i32x4 b = *(const i32x4*)(qw + base + 4);
    u16x8 o;
#pragma unroll
    for (int j = 0; j < 4; ++j) {
        o[j]     = f32_f16((float)(a[j] - z) * s);
        o[4 + j] = f32_f16((float)(b[j] - z) * s);
    }
    *(u16x8*)(outW + base) = o;
}

// ---------------- fused prepare: cast x + dequant Wq/Wk/Wv ------------------
__global__ __launch_bounds__(256) void k_prep_all(
    const float* __restrict__ hs, unsigned short* __restrict__ x16,
    const int* __restrict__ qqw, const float* __restrict__ qsc, const int* __restrict__ qzp,
    const int* __restrict__ kqw, const float* __restrict__ ksc, const int* __restrict__ kzp,
    const int* __restrict__ vqw, const float* __restrict__ vsc, const int* __restrict__ vzp,
    unsigned short* __restrict__ wbuf) {
    const int b = blockIdx.x, tid = threadIdx.x;
    if (b < 8192) {
        int i = (b * 256 + tid) * 4;
        fvec4 v = *(const fvec4*)(hs + i);
        u16x4 o;
#pragma unroll
        for (int j = 0; j < 4; ++j) o[j] = f32_f16(v[j]);
        *(u16x4*)(x16 + i) = o;
    } else if (b < 16384) {
        prep_body(qqw, qsc, qzp, wbuf, b - 8192, tid);
    } else if (b < 18432) {
        prep_body(kqw, ksc, kzp, wbuf + (size_t)4096 * 4096, b - 16384, tid);
    } else {
        prep_body(vqw, vsc, vzp, wbuf + (size_t)5120 * 4096, b - 18432, tid);
    }
}

// ---------------- standalone W4 dequant (Wo; reuses wbuf after QKV GEMM) ----
__global__ __launch_bounds__(256) void k_prep(const int* __restrict__ qw,
                                              const float* __restrict__ sc,
                                              const int* __restrict__ zp,
                                              unsigned short* __restrict__ outW) {
    prep_body(qw, sc, zp, outW, blockIdx.x, threadIdx.x);
}

// ---------------- f16 GEMM A: 256xBN tile, BK=32, ring-3, counted vmcnt -----
// r12-verified skeleton. NEW (r17): lid->(m,n) swapped so each XCD owns an
// n-slice of B (4 n-tiles x 8KB/row-tile ~ 6MB, mostly L2-resident) and
// shares A (16MB) via L3 -> per-XCD L2-miss traffic 50MB -> 22MB. Bijective.
template <typename CT, int NREP>
__global__ __launch_bounds__(512) void k_gemm8(const unsigned short* __restrict__ A,
                                               const unsigned short* __restrict__ B,
                                               CT* __restrict__ C, int N) {
    constexpr int K = 4096, BK = 32, NT = K / BK;
    constexpr int BN = NREP * 64;
    __shared__ __align__(16) unsigned short Al[3][256 * 32];
    __shared__ __align__(16) unsigned short Bl[3][BN * 32];
    const int nbx = N / BN;
    const int tot = nbx * (int)gridDim.y;
    const int hg  = (int)blockIdx.x + (int)blockIdx.y * nbx;
    const int lid = (hg & 7) * (tot >> 3) + (hg >> 3);   // XCD swizzle (tot%8==0)
    const int m0 = (lid % (int)gridDim.y) * 256;         // XCD spans all m
    const int n0 = (lid / (int)gridDim.y) * BN;          // XCD owns n-slice
    const int tid = threadIdx.x;
    const int w = tid >> 6, lane = tid & 63;
    const int wm = w >> 2, wn = w & 3;
    const int lq = lane & 15, lg = lane >> 4;
    const int cx = (lg ^ ((lq >> 1) & 3)) << 3;             // swizzled read chunk
    const int srow = lane >> 2;                             // staging row sub (0..15)
    const int gc = (((lane & 3) ^ ((lane >> 3) & 3)) << 3); // swizzled source col
    f32x4 acc[8][NREP] = {};

    auto stage = [&](int k0, int sl) {
#pragma unroll
        for (int j = 0; j < 2; ++j)
            load_lds16(A + (long long)(m0 + (j * 8 + w) * 16 + srow) * K + k0 + gc,
                       &Al[sl][(j * 8 + w) * 512]);
        if constexpr (NREP == 4) {
#pragma unroll
            for (int j = 0; j < 2; ++j)
                load_lds16(B + (long long)(n0 + (j * 8 + w) * 16 + srow) * K + k0 + gc,
                           &Bl[sl][(j * 8 + w) * 512]);
        } else if constexpr (NREP == 3) {
            if (w < 4) {
#pragma unroll
                for (int i = 0; i < 2; ++i) {
                    const int r0 = w * 32 + i * 16;
                    load_lds16(B + (long long)(n0 + r0 + srow) * K + k0 + gc,
                               &Bl[sl][r0 * 32]);
                }
            } else {
                const int r0 = 128 + (w - 4) * 16;
                load_lds16(B + (long long)(n0 + r0 + srow) * K + k0 + gc,
                           &Bl[sl][r0 * 32]);
            }
        } else {
            load_lds16(B + (long long)(n0 + w * 16 + srow) * K + k0 + gc,
                       &Bl[sl][w * 512]);
        }
    };

    stage(0, 0);
    stage(BK, 1);
    int cs = 0, ss = 2;
    for (int kt = 0; kt < NT; ++kt) {
        if (kt < NT - 1) {
            if constexpr (NREP == 3) {
                if (w < 4) asm volatile("s_waitcnt vmcnt(4)" ::: "memory");
                else       asm volatile("s_waitcnt vmcnt(3)" ::: "memory");
            } else if constexpr (NREP == 4) {
                asm volatile("s_waitcnt vmcnt(4)" ::: "memory");
            } else {
                asm volatile("s_waitcnt vmcnt(3)" ::: "memory");
            }
        } else {
            asm volatile("s_waitcnt vmcnt(0)" ::: "memory");
        }
        __builtin_amdgcn_s_barrier();
        __builtin_amdgcn_sched_barrier(0);
        if (kt + 2 < NT) stage((kt + 2) * BK, ss);
        f16x8 af[8], bf[NREP];
#pragma unroll
        for (int i = 0; i < 8; ++i)
            af[i] = *(const f16x8*)(&Al[cs][(wm * 128 + i * 16 + lq) * 32 + cx]);
#pragma unroll
        for (int i = 0; i < NREP; ++i)
            bf[i] = *(const f16x8*)(&Bl[cs][(wn * (NREP * 16) + i * 16 + lq) * 32 + cx]);
        __builtin_amdgcn_s_setprio(1);
#pragma unroll
        for (int mi = 0; mi < 8; ++mi)
#pragma unroll
            for (int ni = 0; ni < NREP; ++ni)
                acc[mi][ni] = mfma16(af[mi], bf[ni], acc[mi][ni]);
        __builtin_amdgcn_s_setprio(0);
        __builtin_amdgcn_sched_barrier(0);
        if (++cs == 3) cs = 0;
        if (++ss == 3) ss = 0;
    }
#pragma unroll
    for (int mi = 0; mi < 8; ++mi)
#pragma unroll
        for (int ni = 0; ni < NREP; ++ni)
#pragma unroll
            for (int r = 0; r < 4; ++r) {
                const int row = m0 + wm * 128 + mi * 16 + lg * 4 + r;
                const int col = n0 + wn * (NREP * 16) + ni * 16 + lq;
                const float v = acc[mi][ni][r];
                if constexpr (sizeof(CT) == 2) C[(long long)row * N + col] = (CT)f32_f16(v);
                else                           C[(long long)row * N + col] = v;
            }
}

// ---------------- f16 GEMM B: 128x256 tile, BK=64, ring-3, counted vmcnt ----
// r12-verified skeleton. NEW (r17): lid->(m,n) swapped -> each XCD owns 2
// n-tiles of B (4MB, L2-fits) and shares A via L3 (34MB -> 20MB L2-miss).
template <typename CT>
__global__ __launch_bounds__(512) void k_gemm2(const unsigned short* __restrict__ A,
                                               const unsigned short* __restrict__ B,
                                               CT* __restrict__ C, int N) {
    constexpr int K = 4096, BK = 64, NT = K / BK;
    __shared__ __align__(16) unsigned short Al[3][128 * 64];
    __shared__ __align__(16) unsigned short Bl[3][256 * 64];
    const int nbx = N / 256;
    const int tot = nbx * (int)gridDim.y;
    const int hg  = (int)blockIdx.x + (int)blockIdx.y * nbx;
    const int lid = (hg & 7) * (tot >> 3) + (hg >> 3);   // XCD swizzle (tot%8==0)
    const int m0 = (lid % (int)gridDim.y) * 128;         // XCD spans all m
    const int n0 = (lid / (int)gridDim.y) * 256;         // XCD owns n-slice
    const int tid = threadIdx.x;
    const int w = tid >> 6, lane = tid & 63;
    const int wm = w >> 2, wn = w & 3;
    const int lq = lane & 15, lg = lane >> 4;
    const int rsub = lane >> 3;                    // staging row sub (0..7)
    const int gch  = ((lane & 7) ^ rsub) << 3;     // swizzled source col (f16)
    f32x4 acc[4][4] = {};

    auto stage = [&](int k0, int sl) {
#pragma unroll
        for (int i = 0; i < 2; ++i) {
            const int r0 = w * 16 + i * 8;
            load_lds16(A + (long long)(m0 + r0 + rsub) * K + k0 + gch, &Al[sl][r0 * 64]);
        }
#pragma unroll
        for (int i = 0; i < 4; ++i) {
            const int r0 = w * 32 + i * 8;
            load_lds16(B + (long long)(n0 + r0 + rsub) * K + k0 + gch, &Bl[sl][r0 * 64]);
        }
    };

    stage(0, 0);
    stage(BK, 1);
    int cs = 0, ss = 2;
    for (int kt = 0; kt < NT; ++kt) {
        if (kt < NT - 1) asm volatile("s_waitcnt vmcnt(6)" ::: "memory");
        else             asm volatile("s_waitcnt vmcnt(0)" ::: "memory");
        __builtin_amdgcn_s_barrier();
        __builtin_amdgcn_sched_barrier(0);
        if (kt + 2 < NT) stage((kt + 2) * BK, ss);
        f16x8 af[4][2], bf[4][2];
#pragma unroll
        for (int i = 0; i < 4; ++i)
#pragma unroll
            for (int kk = 0; kk < 2; ++kk) {
                const int ar = wm * 64 + i * 16 + lq;
                const int br = wn * 64 + i * 16 + lq;
                af[i][kk] = *(const f16x8*)(&Al[cs][ar * 64 + (((kk * 4 + lg) ^ (lq & 7)) << 3)]);
                bf[i][kk] = *(const f16x8*)(&Bl[cs][br * 64 + (((kk * 4 + lg) ^ (lq & 7)) << 3)]);
            }
        __builtin_amdgcn_s_setprio(1);
#pragma unroll
        for (int mi = 0; mi < 4; ++mi)
#pragma unroll
            for (int ni = 0; ni < 4; ++ni)
#pragma unroll
                for (int kk = 0; kk < 2; ++kk)
                    acc[mi][ni] = mfma16(af[mi][kk], bf[ni][kk], acc[mi][ni]);
        __builtin_amdgcn_s_setprio(0);
        __builtin_amdgcn_sched_barrier(0);
        if (++cs == 3) cs = 0;
        if (++ss == 3) ss = 0;
    }
#pragma unroll
    for (int mi = 0; mi < 4; ++mi)
#pragma unroll
        for (int ni = 0; ni < 4; ++ni)
#pragma unroll
            for (int r = 0; r < 4; ++r) {
                const int row = m0 + wm * 64 + mi * 16 + lg * 4 + r;
                const int col = n0 + wn * 64 + ni * 16 + lq;
                const float v = acc[mi][ni][r];
                if constexpr (sizeof(CT) == 2) C[(long long)row * N + col] = (CT)f32_f16(v);
                else                           C[(long long)row * N + col] = v;
            }
}

// ---------------- V transpose -> tiled layout VT2[hk][t][128][32] -----------
// VT2 tile t holds V^T for keys [32t, 32t+32): row d (128), col = key offset.
// Per-tile 8KB contiguous -> attention PV reads are fully coalesced 1KB/wave.
__global__ __launch_bounds__(256) void k_transpose_v(const unsigned short* __restrict__ QKV,
                                                     unsigned short* __restrict__ VT) {
    __shared__ unsigned short tile[32][33];
    const int s0 = blockIdx.x * 32, d0 = blockIdx.y * 32, hk = blockIdx.z;
    const int tx = threadIdx.x & 31, ty = threadIdx.x >> 5;
#pragma unroll
    for (int j = 0; j < 4; ++j)
        tile[ty + j * 8][tx] =
            QKV[(long long)(s0 + ty + j * 8) * QKVW + (NHD + KVD) + hk * 128 + d0 + tx];
    __syncthreads();
#pragma unroll
    for (int j = 0; j < 4; ++j)
        VT[(((long long)hk * 64 + (s0 >> 5)) * 128 + d0 + ty + j * 8) * 32 + tx] =
            tile[tx][ty + j * 8];
}

// ---------------- causal GQA flash attention (cooperative, f16) -------------
// r8-verified structure, r17 change: V read directly from L2 in TILED layout
// (no Vs LDS stage). Per tile, all 8 V fragments (contiguous 1KB/wave,
// L1-shared by the 4 waves) are issued right after the barrier so QK^T +
// softmax (~500cy) hides the latency. LDS 21.4KB. K staging unchanged.
__global__ __launch_bounds__(256, 4) void k_attn(const unsigned short* __restrict__ QKV,
                                                 const unsigned short* __restrict__ VT,
                                                 unsigned short* __restrict__ O) {
    __shared__ __align__(16) unsigned short Ks[2][32 * 128];
    __shared__ __align__(16) unsigned short Ps[4][16 * 40];
    const int bid = blockIdx.x;
    const int hkv = bid & 7;
    const int tq  = bid >> 3;
    const int g   = (tq < 64) ? tq : 191 - tq;
    const int nt  = (g >> 1) + 1;
    const int q0  = g * 16;
    const int tid = threadIdx.x;
    const int w = tid >> 6, lane = tid & 63;
    const int lq = lane & 15, lg = lane >> 4;
    const int h = hkv * 4 + w;

    const unsigned short* Kg  = QKV + NHD + hkv * 128;
    const unsigned short* VTg = VT + (long long)hkv * (64 * 128 * 32);

    const int ksr = lane >> 4;          // K stage: row sub (0..3)
    const int ksc = lane & 15;          // K stage: 16B chunk (0..15)

    f16x8 qf[4];
    const unsigned short* qp = QKV + (long long)(q0 + lq) * QKVW + h * 128;
#pragma unroll
    for (int kc = 0; kc < 4; ++kc) qf[kc] = *(const f16x8*)(qp + kc * 32 + lg * 8);

    f32x4 oacc[8] = {};
    float m[4], l[4];
#pragma unroll
    for (int r = 0; r < 4; ++r) { m[r] = -1e30f; l[r] = 0.f; }

    auto stage = [&](int j0, int b) {
#pragma unroll
        for (int i = 0; i < 2; ++i) {
            const int r = 8 * w + 4 * i + ksr;
            load_lds16(Kg + (long long)(j0 + r) * QKVW + ((ksc ^ (r & 7)) << 3),
                       &Ks[b][(8 * w + 4 * i) * 128]);
        }
    };

    stage(0, 0);
    int buf = 0;
    for (int t = 0; t < nt; ++t) {
        const int j0 = t * 32;
        __syncthreads();
        if (t + 1 < nt) stage(j0 + 32, buf ^ 1);

        // V tile for this step: issue early (consumed after softmax)
        f16x8 vf[8];
        const unsigned short* vtp = VTg + (long long)t * (128 * 32);
#pragma unroll
        for (int nb = 0; nb < 8; ++nb)
            vf[nb] = *(const f16x8*)(vtp + (nb * 16 + lq) * 32 + lg * 8);

        f32x4 sv[2] = {};
        __builtin_amdgcn_s_setprio(1);
#pragma unroll
        for (int kc = 0; kc < 4; ++kc)
#pragma unroll
            for (int jj = 0; jj < 2; ++jj) {
                const int c = (kc * 4 + lg) ^ (lq & 7);
                f16x8 kf = *(const f16x8*)&Ks[buf][(jj * 16 + lq) * 128 + c * 8];
                sv[jj] = mfma16(qf[kc], kf, sv[jj]);
            }
        __builtin_amdgcn_s_setprio(0);

        float t0a[4], t1a[4], pl[4];
        const bool diag = (t == nt - 1);
#pragma unroll
        for (int r = 0; r < 4; ++r) {
            float t0 = sv[0][r] * SCALE_LOG2E;
            float t1 = sv[1][r] * SCALE_LOG2E;
            if (diag) {
                const int qg = q0 + lg * 4 + r;
                if (j0 + lq > qg)      t0 = -INFINITY;
                if (j0 + 16 + lq > qg) t1 = -INFINITY;
            }
            t0a[r] = t0; t1a[r] = t1;
            pl[r] = fmaxf(t0, t1);
        }
        const bool grow = (pl[0] > m[0] + 8.f) || (pl[1] > m[1] + 8.f) ||
                          (pl[2] > m[2] + 8.f) || (pl[3] > m[3] + 8.f);
        if (__any(grow)) {
#pragma unroll
            for (int r = 0; r < 4; ++r) {
                float mx = pl[r];
                mx = fmaxf(mx, __shfl_xor(mx, 1));
                mx = fmaxf(mx, __shfl_xor(mx, 2));
                mx = fmaxf(mx, __shfl_xor(mx, 4));
                mx = fmaxf(mx, __shfl_xor(mx, 8));
                const float mn = fmaxf(m[r], mx);
                const float alpha = exp2f(m[r] - mn);
                m[r] = mn;
                l[r] *= alpha;
#pragma unroll
                for (int nb = 0; nb < 8; ++nb) oacc[nb][r] *= alpha;
            }
        }
#pragma unroll
        for (int r = 0; r < 4; ++r) {
            const float p0 = exp2f(t0a[r] - m[r]);
            const float p1 = exp2f(t1a[r] - m[r]);
            l[r] += p0 + p1;
            Ps[w][(lg * 4 + r) * 40 + lq]      = f32_f16(p0);
            Ps[w][(lg * 4 + r) * 40 + 16 + lq] = f32_f16(p1);
        }
        const f16x8 pf = *(const f16x8*)&Ps[w][lq * 40 + lg * 8];
        __builtin_amdgcn_s_setprio(1);
#pragma unroll
        for (int nb = 0; nb < 8; ++nb)
            oacc[nb] = mfma16(pf, vf[nb], oacc[nb]);
        __builtin_amdgcn_s_setprio(0);
        buf ^= 1;
    }

    float linv[4];
#pragma unroll
    for (int r = 0; r < 4; ++r) {
        float s = l[r];
        s += __shfl_xor(s, 1);
        s += __shfl_xor(s, 2);
        s += __shfl_xor(s, 4);
        s += __shfl_xor(s, 8);
        linv[r] = 1.0f / s;
    }
#pragma unroll
    for (int nb = 0; nb < 8; ++nb)
#pragma unroll
        for (int r = 0; r < 4; ++r) {
            const int row = q0 + lg * 4 + r;
            const int col = h * 128 + nb * 16 + lq;
            O[(long long)row * NHD + col] = f32_f16(oacc[nb][r] * linv[r]);
        }
}

extern "C" void kernel_launch(void* const* d_in, const int* in_sizes, int n_in,
                              void* d_out, int out_size, void* d_ws, size_t ws_size,
                              hipStream_t stream) {
    (void)in_sizes; (void)n_in; (void)out_size; (void)ws_size;
    const float* hs  = (const float*)d_in[0];
    const int*   qqw = (const int*)d_in[1];
    const float* qsc = (const float*)d_in[2];
    const int*   qzp = (const int*)d_in[3];
    const int*   kqw = (const int*)d_in[4];
    const float* ksc = (const float*)d_in[5];
    const int*   kzp = (const int*)d_in[6];
    const int*   vqw = (const int*)d_in[7];
    const float* vsc = (const float*)d_in[8];
    const int*   vzp = (const int*)d_in[9];
    const int*   oqw = (const int*)d_in[10];
    const float* osc = (const float*)d_in[11];
    const int*   ozp = (const int*)d_in[12];

    char* ws = (char*)d_ws;
    // ws layout (bytes):
    //   x16  : 0        .. 16MB    (2048x4096 f16 activations)
    //   wbuf : 16MB     .. 64MB    (6144x4096 f16 dequant W; later Wo)
    //   vt   : 65MB     .. 69MB    (8x64x128x32 f16 tiled V^T)
    //   xatt : 69MB     .. 85MB    (2048x4096 f16 attention output)
    unsigned short* x16  = (unsigned short*)(ws);
    unsigned short* wbuf = (unsigned short*)(ws + (16ULL << 20));
    unsigned short* vt   = (unsigned short*)(ws + (65ULL << 20));
    unsigned short* xatt = (unsigned short*)(ws + (69ULL << 20));
    unsigned short* qkv  = (unsigned short*)d_out;   // 2048x6144 f16 scratch in d_out
    float* out = (float*)d_out;

    // fused: cast x (blocks 0..8191) + dequant Wq/Wk/Wv (blocks 8192..20479)
    k_prep_all<<<20480, 256, 0, stream>>>(hs, x16, qqw, qsc, qzp,
                                          kqw, ksc, kzp, vqw, vsc, vzp, wbuf);
    // fused QKV projection (f16): 256x192 tiles, 32x8 = 256 blocks = 1/CU exact
    k_gemm8<unsigned short, 3><<<dim3(32, 8), 512, 0, stream>>>(x16, wbuf, qkv, QKVW);
    k_transpose_v<<<dim3(64, 4, 8), 256, 0, stream>>>(qkv, vt);
    // Wo dequant (reuses wbuf; QKV GEMM already done)
    k_prep<<<8192, 256, 0, stream>>>(oqw, osc, ozp, wbuf);
    // attention -> xatt
    k_attn<<<1024, 256, 0, stream>>>(qkv, vt, xatt);
    // O projection (f32 out): 128x256 tiles BK=64, 16x16 = 256 blocks = 1/CU
    k_gemm2<float><<<dim3(16, 16), 512, 0, stream>>>(xatt, wbuf, out, 4096);
}

// Round 18
// 302.759 us; speedup vs baseline: 1.1360x; 1.1360x over previous
//
#include <hip/hip_runtime.h>
#include <stdint.h>

#define DI __device__ __forceinline__

typedef __attribute__((ext_vector_type(8))) _Float16 f16x8;
typedef __attribute__((ext_vector_type(4))) float f32x4;
typedef __attribute__((ext_vector_type(4))) int   i32x4;
typedef __attribute__((ext_vector_type(4))) float fvec4;
typedef __attribute__((ext_vector_type(8))) unsigned short u16x8;
typedef __attribute__((ext_vector_type(4))) unsigned short u16x4;

constexpr int S2   = 2048;
constexpr int NHD  = 4096;   // NH*HD (q width)
constexpr int KVD  = 1024;   // NKV*HD
constexpr int QKVW = 6144;   // q+k+v fused width
constexpr float SCALE_LOG2E = 0.08838834764831845f * 1.4426950408889634f; // 1/sqrt(128)*log2(e)

DI unsigned short f32_f16(float f) {
    union { _Float16 h; unsigned short u; } v;
    v.h = (_Float16)f;
    return v.u;
}

DI f32x4 mfma16(f16x8 a, f16x8 b, f32x4 c) {
    return __builtin_amdgcn_mfma_f32_16x16x32_f16(a, b, c, 0, 0, 0);
}

DI void load_lds16(const void* g, void* l) {
    __builtin_amdgcn_global_load_lds(
        (const __attribute__((address_space(1))) void*)(uintptr_t)g,
        (__attribute__((address_space(3))) void*)(uintptr_t)l, 16, 0, 0);
}

// ---------------- W4 dequant body: (q - z) * s -> f16 -----------------------
DI void prep_body(const int* __restrict__ qw, const float* __restrict__ sc,
                  const int* __restrict__ zp, unsigned short* __restrict__ outW,
                  int blk, int tid) {
    long long t = (long long)blk * 256 + tid;
    long long base = t * 8;
    int n = (int)(base >> 12);
    int g = (int)((base >> 7) & 31);
    float s = sc[n * 32 + g];
    int   z = zp[n * 32 + g];
    i32x4 a = *(const i32x4*)(qw + base);
    i32x4 b = *(const i32x4*)(qw + base + 4);
    u16x8 o;
#pragma unroll
    for (int j = 0; j < 4; ++j) {
        o[j]     = f32_f16((float)(a[j] - z) * s);
        o[4 + j] = f32_f16((float)(b[j] - z) * s);
    }
    *(u16x8*)(outW + base) = o;
}

// ---------------- fused prepare: cast x + dequant Wq/Wk/Wv ------------------
__global__ __launch_bounds__(256) void k_prep_all(
    const float* __restrict__ hs, unsigned short* __restrict__ x16,
    const int* __restrict__ qqw, const float* __restrict__ qsc, const int* __restrict__ qzp,
    const int* __restrict__ kqw, const float* __restrict__ ksc, const int* __restrict__ kzp,
    const int* __restrict__ vqw, const float* __restrict__ vsc, const int* __restrict__ vzp,
    unsigned short* __restrict__ wbuf) {
    const int b = blockIdx.x, tid = threadIdx.x;
    if (b < 8192) {
        int i = (b * 256 + tid) * 4;
        fvec4 v = *(const fvec4*)(hs + i);
        u16x4 o;
#pragma unroll
        for (int j = 0; j < 4; ++j) o[j] = f32_f16(v[j]);
        *(u16x4*)(x16 + i) = o;
    } else if (b < 16384) {
        prep_body(qqw, qsc, qzp, wbuf, b - 8192, tid);
    } else if (b < 18432) {
        prep_body(kqw, ksc, kzp, wbuf + (size_t)4096 * 4096, b - 16384, tid);
    } else {
        prep_body(vqw, vsc, vzp, wbuf + (size_t)5120 * 4096, b - 18432, tid);
    }
}

// ---------------- standalone W4 dequant (Wo; reuses wbuf after QKV GEMM) ----
__global__ __launch_bounds__(256) void k_prep(const int* __restrict__ qw,
                                              const float* __restrict__ sc,
                                              const int* __restrict__ zp,
                                              unsigned short* __restrict__ outW) {
    prep_body(qw, sc, zp, outW, blockIdx.x, threadIdx.x);
}

// ---------------- f16 GEMM A: 256xBN tile, BK=32, ring-3, counted vmcnt -----
// r12-verified skeleton + r17-verified lid->(m,n) swap: each XCD owns an
// n-slice of B (L2-resident) and shares A via L3 (~16us measured win).
template <typename CT, int NREP>
__global__ __launch_bounds__(512) void k_gemm8(const unsigned short* __restrict__ A,
                                               const unsigned short* __restrict__ B,
                                               CT* __restrict__ C, int N) {
    constexpr int K = 4096, BK = 32, NT = K / BK;
    constexpr int BN = NREP * 64;
    __shared__ __align__(16) unsigned short Al[3][256 * 32];
    __shared__ __align__(16) unsigned short Bl[3][BN * 32];
    const int nbx = N / BN;
    const int tot = nbx * (int)gridDim.y;
    const int hg  = (int)blockIdx.x + (int)blockIdx.y * nbx;
    const int lid = (hg & 7) * (tot >> 3) + (hg >> 3);   // XCD swizzle (tot%8==0)
    const int m0 = (lid % (int)gridDim.y) * 256;         // XCD spans all m
    const int n0 = (lid / (int)gridDim.y) * BN;          // XCD owns n-slice
    const int tid = threadIdx.x;
    const int w = tid >> 6, lane = tid & 63;
    const int wm = w >> 2, wn = w & 3;
    const int lq = lane & 15, lg = lane >> 4;
    const int cx = (lg ^ ((lq >> 1) & 3)) << 3;             // swizzled read chunk
    const int srow = lane >> 2;                             // staging row sub (0..15)
    const int gc = (((lane & 3) ^ ((lane >> 3) & 3)) << 3); // swizzled source col
    f32x4 acc[8][NREP] = {};

    auto stage = [&](int k0, int sl) {
#pragma unroll
        for (int j = 0; j < 2; ++j)
            load_lds16(A + (long long)(m0 + (j * 8 + w) * 16 + srow) * K + k0 + gc,
                       &Al[sl][(j * 8 + w) * 512]);
        if constexpr (NREP == 4) {
#pragma unroll
            for (int j = 0; j < 2; ++j)
                load_lds16(B + (long long)(n0 + (j * 8 + w) * 16 + srow) * K + k0 + gc,
                           &Bl[sl][(j * 8 + w) * 512]);
        } else if constexpr (NREP == 3) {
            if (w < 4) {
#pragma unroll
                for (int i = 0; i < 2; ++i) {
                    const int r0 = w * 32 + i * 16;
                    load_lds16(B + (long long)(n0 + r0 + srow) * K + k0 + gc,
                               &Bl[sl][r0 * 32]);
                }
            } else {
                const int r0 = 128 + (w - 4) * 16;
                load_lds16(B + (long long)(n0 + r0 + srow) * K + k0 + gc,
                           &Bl[sl][r0 * 32]);
            }
        } else {
            load_lds16(B + (long long)(n0 + w * 16 + srow) * K + k0 + gc,
                       &Bl[sl][w * 512]);
        }
    };

    stage(0, 0);
    stage(BK, 1);
    int cs = 0, ss = 2;
    for (int kt = 0; kt < NT; ++kt) {
        if (kt < NT - 1) {
            if constexpr (NREP == 3) {
                if (w < 4) asm volatile("s_waitcnt vmcnt(4)" ::: "memory");
                else       asm volatile("s_waitcnt vmcnt(3)" ::: "memory");
            } else if constexpr (NREP == 4) {
                asm volatile("s_waitcnt vmcnt(4)" ::: "memory");
            } else {
                asm volatile("s_waitcnt vmcnt(3)" ::: "memory");
            }
        } else {
            asm volatile("s_waitcnt vmcnt(0)" ::: "memory");
        }
        __builtin_amdgcn_s_barrier();
        __builtin_amdgcn_sched_barrier(0);
        if (kt + 2 < NT) stage((kt + 2) * BK, ss);
        f16x8 af[8], bf[NREP];
#pragma unroll
        for (int i = 0; i < 8; ++i)
            af[i] = *(const f16x8*)(&Al[cs][(wm * 128 + i * 16 + lq) * 32 + cx]);
#pragma unroll
        for (int i = 0; i < NREP; ++i)
            bf[i] = *(const f16x8*)(&Bl[cs][(wn * (NREP * 16) + i * 16 + lq) * 32 + cx]);
        __builtin_amdgcn_s_setprio(1);
#pragma unroll
        for (int mi = 0; mi < 8; ++mi)
#pragma unroll
            for (int ni = 0; ni < NREP; ++ni)
                acc[mi][ni] = mfma16(af[mi], bf[ni], acc[mi][ni]);
        __builtin_amdgcn_s_setprio(0);
        __builtin_amdgcn_sched_barrier(0);
        if (++cs == 3) cs = 0;
        if (++ss == 3) ss = 0;
    }
#pragma unroll
    for (int mi = 0; mi < 8; ++mi)
#pragma unroll
        for (int ni = 0; ni < NREP; ++ni)
#pragma unroll
            for (int r = 0; r < 4; ++r) {
                const int row = m0 + wm * 128 + mi * 16 + lg * 4 + r;
                const int col = n0 + wn * (NREP * 16) + ni * 16 + lq;
                const float v = acc[mi][ni][r];
                if constexpr (sizeof(CT) == 2) C[(long long)row * N + col] = (CT)f32_f16(v);
                else                           C[(long long)row * N + col] = v;
            }
}

// ---------------- f16 GEMM B: 128x256 tile, BK=64, ring-3, counted vmcnt ----
// r12-verified skeleton + r17-verified lid->(m,n) swap.
template <typename CT>
__global__ __launch_bounds__(512) void k_gemm2(const unsigned short* __restrict__ A,
                                               const unsigned short* __restrict__ B,
                                               CT* __restrict__ C, int N) {
    constexpr int K = 4096, BK = 64, NT = K / BK;
    __shared__ __align__(16) unsigned short Al[3][128 * 64];
    __shared__ __align__(16) unsigned short Bl[3][256 * 64];
    const int nbx = N / 256;
    const int tot = nbx * (int)gridDim.y;
    const int hg  = (int)blockIdx.x + (int)blockIdx.y * nbx;
    const int lid = (hg & 7) * (tot >> 3) + (hg >> 3);   // XCD swizzle (tot%8==0)
    const int m0 = (lid % (int)gridDim.y) * 128;         // XCD spans all m
    const int n0 = (lid / (int)gridDim.y) * 256;         // XCD owns n-slice
    const int tid = threadIdx.x;
    const int w = tid >> 6, lane = tid & 63;
    const int wm = w >> 2, wn = w & 3;
    const int lq = lane & 15, lg = lane >> 4;
    const int rsub = lane >> 3;                    // staging row sub (0..7)
    const int gch  = ((lane & 7) ^ rsub) << 3;     // swizzled source col (f16)
    f32x4 acc[4][4] = {};

    auto stage = [&](int k0, int sl) {
#pragma unroll
        for (int i = 0; i < 2; ++i) {
            const int r0 = w * 16 + i * 8;
            load_lds16(A + (long long)(m0 + r0 + rsub) * K + k0 + gch, &Al[sl][r0 * 64]);
        }
#pragma unroll
        for (int i = 0; i < 4; ++i) {
            const int r0 = w * 32 + i * 8;
            load_lds16(B + (long long)(n0 + r0 + rsub) * K + k0 + gch, &Bl[sl][r0 * 64]);
        }
    };

    stage(0, 0);
    stage(BK, 1);
    int cs = 0, ss = 2;
    for (int kt = 0; kt < NT; ++kt) {
        if (kt < NT - 1) asm volatile("s_waitcnt vmcnt(6)" ::: "memory");
        else             asm volatile("s_waitcnt vmcnt(0)" ::: "memory");
        __builtin_amdgcn_s_barrier();
        __builtin_amdgcn_sched_barrier(0);
        if (kt + 2 < NT) stage((kt + 2) * BK, ss);
        f16x8 af[4][2], bf[4][2];
#pragma unroll
        for (int i = 0; i < 4; ++i)
#pragma unroll
            for (int kk = 0; kk < 2; ++kk) {
                const int ar = wm * 64 + i * 16 + lq;
                const int br = wn * 64 + i * 16 + lq;
                af[i][kk] = *(const f16x8*)(&Al[cs][ar * 64 + (((kk * 4 + lg) ^ (lq & 7)) << 3)]);
                bf[i][kk] = *(const f16x8*)(&Bl[cs][br * 64 + (((kk * 4 + lg) ^ (lq & 7)) << 3)]);
            }
        __builtin_amdgcn_s_setprio(1);
#pragma unroll
        for (int mi = 0; mi < 4; ++mi)
#pragma unroll
            for (int ni = 0; ni < 4; ++ni)
#pragma unroll
                for (int kk = 0; kk < 2; ++kk)
                    acc[mi][ni] = mfma16(af[mi][kk], bf[ni][kk], acc[mi][ni]);
        __builtin_amdgcn_s_setprio(0);
        __builtin_amdgcn_sched_barrier(0);
        if (++cs == 3) cs = 0;
        if (++ss == 3) ss = 0;
    }
#pragma unroll
    for (int mi = 0; mi < 4; ++mi)
#pragma unroll
        for (int ni = 0; ni < 4; ++ni)
#pragma unroll
            for (int r = 0; r < 4; ++r) {
                const int row = m0 + wm * 64 + mi * 16 + lg * 4 + r;
                const int col = n0 + wn * 64 + ni * 16 + lq;
                const float v = acc[mi][ni][r];
                if constexpr (sizeof(CT) == 2) C[(long long)row * N + col] = (CT)f32_f16(v);
                else                           C[(long long)row * N + col] = v;
            }
}

// ---------------- V transpose: VT[hk][d][s] = V[s][hk*128+d] ----------------
__global__ __launch_bounds__(256) void k_transpose_v(const unsigned short* __restrict__ QKV,
                                                     unsigned short* __restrict__ VT) {
    __shared__ unsigned short tile[32][33];
    const int s0 = blockIdx.x * 32, d0 = blockIdx.y * 32, hk = blockIdx.z;
    const int tx = threadIdx.x & 31, ty = threadIdx.x >> 5;
#pragma unroll
    for (int j = 0; j < 4; ++j)
        tile[ty + j * 8][tx] =
            QKV[(long long)(s0 + ty + j * 8) * QKVW + (NHD + KVD) + hk * 128 + d0 + tx];
    __syncthreads();
#pragma unroll
    for (int j = 0; j < 4; ++j)
        VT[((long long)hk * 128 + d0 + ty + j * 8) * S2 + s0 + tx] = tile[tx][ty + j * 8];
}

// ---------------- causal GQA flash attention (cooperative, f16) -------------
// (r16-exact: V^T staged in LDS, verified ~85us)
__global__ __launch_bounds__(256, 4) void k_attn(const unsigned short* __restrict__ QKV,
                                                 const unsigned short* __restrict__ VT,
                                                 unsigned short* __restrict__ O) {
    __shared__ __align__(16) unsigned short Ks[2][32 * 128];
    __shared__ __align__(16) unsigned short Vs[2][128 * 32];
    __shared__ __align__(16) unsigned short Ps[4][16 * 40];
    const int bid = blockIdx.x;
    const int hkv = bid & 7;
    const int tq  = bid >> 3;
    const int g   = (tq < 64) ? tq : 191 - tq;
    const int nt  = (g >> 1) + 1;
    const int q0  = g * 16;
    const int tid = threadIdx.x;
    const int w = tid >> 6, lane = tid & 63;
    const int lq = lane & 15, lg = lane >> 4;
    const int h = hkv * 4 + w;

    const unsigned short* Kg  = QKV + NHD + hkv * 128;
    const unsigned short* VTg = VT + (long long)hkv * 128 * S2;

    const int ksr = lane >> 4;
    const int ksc = lane & 15;
    const int vsr = lane >> 2;
    const int vsc = lane & 3;
    const int vsx = (lane >> 3) & 3;

    f16x8 qf[4];
    const unsigned short* qp = QKV + (long long)(q0 + lq) * QKVW + h * 128;
#pragma unroll
    for (int kc = 0; kc < 4; ++kc) qf[kc] = *(const f16x8*)(qp + kc * 32 + lg * 8);

    f32x4 oacc[8] = {};
    float m[4], l[4];
#pragma unroll
    for (int r = 0; r < 4; ++r) { m[r] = -1e30f; l[r] = 0.f; }

    auto stage = [&](int j0, int b) {
#pragma unroll
        for (int i = 0; i < 2; ++i) {
            const int r = 8 * w + 4 * i + ksr;
            load_lds16(Kg + (long long)(j0 + r) * QKVW + ((ksc ^ (r & 7)) << 3),
                       &Ks[b][(8 * w + 4 * i) * 128]);
        }
#pragma unroll
        for (int i = 0; i < 2; ++i) {
            const int r = 32 * w + 16 * i + vsr;
            load_lds16(VTg + (long long)r * S2 + j0 + ((vsc ^ vsx) << 3),
                       &Vs[b][(32 * w + 16 * i) * 32]);
        }
    };

    stage(0, 0);
    int buf = 0;
    for (int t = 0; t < nt; ++t) {
        const int j0 = t * 32;
        __syncthreads();
        if (t + 1 < nt) stage(j0 + 32, buf ^ 1);

        f32x4 sv[2] = {};
        __builtin_amdgcn_s_setprio(1);
#pragma unroll
        for (int kc = 0; kc < 4; ++kc)
#pragma unroll
            for (int jj = 0; jj < 2; ++jj) {
                const int c = (kc * 4 + lg) ^ (lq & 7);
                f16x8 kf = *(const f16x8*)&Ks[buf][(jj * 16 + lq) * 128 + c * 8];
                sv[jj] = mfma16(qf[kc], kf, sv[jj]);
            }
        __builtin_amdgcn_s_setprio(0);

        float t0a[4], t1a[4], pl[4];
        const bool diag = (t == nt - 1);
#pragma unroll
        for (int r = 0; r < 4; ++r) {
            float t0 = sv[0][r] * SCALE_LOG2E;
            float t1 = sv[1][r] * SCALE_LOG2E;
            if (diag) {
                const int qg = q0 + lg * 4 + r;
                if (j0 + lq > qg)      t0 = -INFINITY;
                if (j0 + 16 + lq > qg) t1 = -INFINITY;
            }
            t0a[r] = t0; t1a[r] = t1;
            pl[r] = fmaxf(t0, t1);
        }
        const bool grow = (pl[0] > m[0] + 8.f) || (pl[1] > m[1] + 8.f) ||
                          (pl[2] > m[2] + 8.f) || (pl[3] > m[3] + 8.f);
        if (__any(grow)) {
#pragma unroll
            for (int r = 0; r < 4; ++r) {
                float mx = pl[r];
                mx = fmaxf(mx, __shfl_xor(mx, 1));
                mx = fmaxf(mx, __shfl_xor(mx, 2));
                mx = fmaxf(mx, __shfl_xor(mx, 4));
                mx = fmaxf(mx, __shfl_xor(mx, 8));
                const float mn = fmaxf(m[r], mx);
                const float alpha = exp2f(m[r] - mn);
                m[r] = mn;
                l[r] *= alpha;
#pragma unroll
                for (int nb = 0; nb < 8; ++nb) oacc[nb][r] *= alpha;
            }
        }
#pragma unroll
        for (int r = 0; r < 4; ++r) {
            const float p0 = exp2f(t0a[r] - m[r]);
            const float p1 = exp2f(t1a[r] - m[r]);
            l[r] += p0 + p1;
            Ps[w][(lg * 4 + r) * 40 + lq]      = f32_f16(p0);
            Ps[w][(lg * 4 + r) * 40 + 16 + lq] = f32_f16(p1);
        }
        const f16x8 pf = *(const f16x8*)&Ps[w][lq * 40 + lg * 8];
        __builtin_amdgcn_s_setprio(1);
#pragma unroll
        for (int nb = 0; nb < 8; ++nb) {
            const int c = lg ^ ((lq >> 1) & 3);
            f16x8 vf = *(const f16x8*)&Vs[buf][(nb * 16 + lq) * 32 + c * 8];
            oacc[nb] = mfma16(pf, vf, oacc[nb]);
        }
        __builtin_amdgcn_s_setprio(0);
        buf ^= 1;
    }

    float linv[4];
#pragma unroll
    for (int r = 0; r < 4; ++r) {
        float s = l[r];
        s += __shfl_xor(s, 1);
        s += __shfl_xor(s, 2);
        s += __shfl_xor(s, 4);
        s += __shfl_xor(s, 8);
        linv[r] = 1.0f / s;
    }
#pragma unroll
    for (int nb = 0; nb < 8; ++nb)
#pragma unroll
        for (int r = 0; r < 4; ++r) {
            const int row = q0 + lg * 4 + r;
            const int col = h * 128 + nb * 16 + lq;
            O[(long long)row * NHD + col] = f32_f16(oacc[nb][r] * linv[r]);
        }
}

extern "C" void kernel_launch(void* const* d_in, const int* in_sizes, int n_in,
                              void* d_out, int out_size, void* d_ws, size_t ws_size,
                              hipStream_t stream) {
    (void)in_sizes; (void)n_in; (void)out_size; (void)ws_size;
    const float* hs  = (const float*)d_in[0];
    const int*   qqw = (const int*)d_in[1];
    const float* qsc = (const float*)d_in[2];
    const int*   qzp = (const int*)d_in[3];
    const int*   kqw = (const int*)d_in[4];
    const float* ksc = (const float*)d_in[5];
    const int*   kzp = (const int*)d_in[6];
    const int*   vqw = (const int*)d_in[7];
    const float* vsc = (const float*)d_in[8];
    const int*   vzp = (const int*)d_in[9];
    const int*   oqw = (const int*)d_in[10];
    const float* osc = (const float*)d_in[11];
    const int*   ozp = (const int*)d_in[12];

    char* ws = (char*)d_ws;
    // ws layout (bytes):
    //   x16  : 0        .. 16MB    (2048x4096 f16 activations)
    //   wbuf : 16MB     .. 64MB    (6144x4096 f16 dequant W; later Wo)
    //   vt   : 65MB     .. 69MB    (8x128x2048 f16 V^T)
    //   xatt : 69MB     .. 85MB    (2048x4096 f16 attention output)
    unsigned short* x16  = (unsigned short*)(ws);
    unsigned short* wbuf = (unsigned short*)(ws + (16ULL << 20));
    unsigned short* vt   = (unsigned short*)(ws + (65ULL << 20));
    unsigned short* xatt = (unsigned short*)(ws + (69ULL << 20));
    unsigned short* qkv  = (unsigned short*)d_out;   // 2048x6144 f16 scratch in d_out
    float* out = (float*)d_out;

    // fused: cast x (blocks 0..8191) + dequant Wq/Wk/Wv (blocks 8192..20479)
    k_prep_all<<<20480, 256, 0, stream>>>(hs, x16, qqw, qsc, qzp,
                                          kqw, ksc, kzp, vqw, vsc, vzp, wbuf);
    // fused QKV projection (f16): 256x192 tiles, 32x8 = 256 blocks = 1/CU exact
    k_gemm8<unsigned short, 3><<<dim3(32, 8), 512, 0, stream>>>(x16, wbuf, qkv, QKVW);
    k_transpose_v<<<dim3(64, 4, 8), 256, 0, stream>>>(qkv, vt);
    // Wo dequant (reuses wbuf; QKV GEMM already done)
    k_prep<<<8192, 256, 0, stream>>>(oqw, osc, ozp, wbuf);
    // attention -> xatt
    k_attn<<<1024, 256, 0, stream>>>(qkv, vt, xatt);
    // O projection (f32 out): 128x256 tiles BK=64, 16x16 = 256 blocks = 1/CU
    k_gemm2<float><<<dim3(16, 16), 512, 0, stream>>>(xatt, wbuf, out, 4096);
}